// Round 16
// baseline (14.282 us; speedup 1.0000x reference)
//
#include <hip/hip_runtime.h>

// Problem constants (fixed by the reference)
#define NROWS   12288   // NUM_INPUT_ROWS
#define NCOLS   256     // CODEBOOK_DIM
#define HID     512     // HIDDEN_DIM
#define NNODES  16384   // NUM_NODES (zero-padded rows contribute nothing)
#define NPART   32      // partial rows (tail Phase A reads [32][256] = 32 KB)
#define NTAIL   32      // tail blocks (16 hidden dims / 16 KB W1 each)
#define TAG32   0xD1B54A33u          // fresh tag
#define TAG64   ((unsigned long long)TAG32 << 32)

// ws float-index layout:
//   [0, 8192)        wsA partials [32][256]
//   [53248, 53312)   flagS[32] (u64 payload flags, 8B aligned)
#define WS_FLOATS_NEEDED 53312

// ---------------------------------------------------------------------------
// K1 (8-way column-split + W1 prime): 256 blocks x 256 threads.
// Identical to R14/R15's proven kernel.
// ---------------------------------------------------------------------------
__global__ __launch_bounds__(256) void colsum_split8(const float* __restrict__ x,
                                                     const float* __restrict__ W1,
                                                     float* __restrict__ wsA) {
    const int t     = threadIdx.x;
    const int c4    = t & 7;             // float4 col within eighth
    const int rofs  = t >> 3;            // 0..31
    const int bid   = blockIdx.x;        // 0..255
    const int prow  = bid & 31;          // partial row
    const int cbase = (bid >> 5) * 8;    // float4 col base: 0,8,...,56
    const float4* __restrict__ x4 = (const float4*)x;

    // ---- W1 L3-prime (independent; overlaps the x-read) ----
    {
        const float4* __restrict__ W1_4 = (const float4*)W1;
        float4 wv = W1_4[(bid & 127) * 256 + t];
        asm volatile("" :: "v"(wv.x), "v"(wv.y), "v"(wv.z), "v"(wv.w));
    }

    // ---- Colsum: rows [prow*384, +384), this block's column-eighth ----
    float4 acc = make_float4(0.f, 0.f, 0.f, 0.f);
    #pragma unroll
    for (int k = 0; k < 12; ++k) {
        const int r = prow * 384 + rofs + k * 32;
        float4 v = x4[r * 64 + cbase + c4];
        acc.x += v.x; acc.y += v.y; acc.z += v.z; acc.w += v.w;
    }

    __shared__ float4 s[256];
    s[t] = acc;
    __syncthreads();
    if (t < 64) {
        float4 a = s[t], b = s[t + 64], c = s[t + 128], d = s[t + 192];
        float4 r;
        r.x = a.x + b.x + c.x + d.x;
        r.y = a.y + b.y + c.y + d.y;
        r.z = a.z + b.z + c.z + d.z;
        r.w = a.w + b.w + c.w + d.w;
        s[t] = r;
    }
    __syncthreads();
    if (t < 8) {
        float4 a = s[t];
        #pragma unroll
        for (int g = 1; g < 8; ++g) {
            float4 v = s[g * 8 + t];
            a.x += v.x; a.y += v.y; a.z += v.z; a.w += v.w;
        }
        ((float4*)wsA)[prow * 64 + cbase + t] = a;
    }
}

// ---------------------------------------------------------------------------
// K2 (tail): 32 blocks x 512 threads. Block b owns hidden dims [b*16, +16)
// -> W1 per block = 16 KB (half of R15's 32 KB leg).
//  Prefetch: thread t (cgroup g=t>>4 in [0,32), dim-lane dl=t&15,
//    d=b*16+dl) loads 8 W1 values W1[(g*8+j)*512 + d] -- 64B coalesced
//    segments, issued before Phase A (latency overlaps via vmcnt FIFO).
//  Phase A: reduce 32 partials -> colmean (identical to R14/R15).
//  Phase B: pa = sum_{j<8} colmean[g*8+j]*w1r[j]; part[t]; combine 32
//    cgroups at t<16; relu; W2 dot; 16-lane shuffle reduce -> flagS[b].
//  Exchange: lanes t<32 poll 32 payload flags; wave-0 fixed-order sum;
//    relu(+b2); fan-out 32 x 128 float4 = 16384 floats.
// Replay safety: proven payload-flag pattern (R10/R13-R15, absmax 0).
// ---------------------------------------------------------------------------
__global__ __launch_bounds__(512) void tail_kernel(const float* __restrict__ wsA,
                                                   const float* __restrict__ W1,
                                                   const float* __restrict__ b1,
                                                   const float* __restrict__ W2,
                                                   const float* __restrict__ b2,
                                                   unsigned long long* __restrict__ flagS,
                                                   float* __restrict__ out) {
    __shared__ float4 tmp4[512];
    __shared__ float  colmean[NCOLS];
    __shared__ float  part[512];
    __shared__ float  sval;

    const int t  = threadIdx.x;
    const int b  = blockIdx.x;       // 0..31
    const int g  = t >> 4;           // cgroup 0..31 -> c range [g*8, +8)
    const int dl = t & 15;           // dim-lane
    const int d  = b * 16 + dl;      // hidden dim

    // ---- Prefetch W1 chunk (8 scalar loads/thread, 64B segments) ----
    float w1r[8];
    #pragma unroll
    for (int j = 0; j < 8; ++j)
        w1r[j] = W1[(g * 8 + j) * HID + d];
    float b1r = 0.f, w2r = 0.f, b2r = 0.f;
    if (t < 16) { b1r = b1[d]; w2r = W2[d]; b2r = b2[0]; }

    // ---- Phase A: reduce 32 partials -> colmean (same as R14/R15) ----
    {
        const int w = t >> 6, l = t & 63;
        const float4* __restrict__ wsA4 = (const float4*)wsA;
        float4 acc = make_float4(0.f, 0.f, 0.f, 0.f);
        #pragma unroll
        for (int j = 0; j < NPART / 8; ++j) {
            float4 v = wsA4[(w * (NPART / 8) + j) * 64 + l];
            acc.x += v.x; acc.y += v.y; acc.z += v.z; acc.w += v.w;
        }
        tmp4[t] = acc;
        __syncthreads();
        if (t < 64) {
            float4 a = tmp4[t];
            #pragma unroll
            for (int gg = 1; gg < 8; ++gg) {
                float4 v = tmp4[gg * 64 + t];
                a.x += v.x; a.y += v.y; a.z += v.z; a.w += v.w;
            }
            const float inv = 1.0f / (float)NNODES;
            a.x *= inv; a.y *= inv; a.z *= inv; a.w *= inv;
            ((float4*)colmean)[t] = a;
        }
        __syncthreads();
    }

    // ---- Phase B: hidden chunk + partial s, publish payload flag ----
    {
        float pa = 0.f;
        #pragma unroll
        for (int j = 0; j < 8; ++j)
            pa = fmaf(colmean[g * 8 + j], w1r[j], pa);
        part[t] = pa;
        __syncthreads();

        if (t < 16) {
            float hs = b1r;
            #pragma unroll
            for (int gg = 0; gg < 32; ++gg)
                hs += part[gg * 16 + t];
            const float h = fmaxf(hs, 0.0f);

            float p = h * w2r;
            #pragma unroll
            for (int off = 8; off > 0; off >>= 1)
                p += __shfl_down(p, off, 16);
            if (t == 0)
                __hip_atomic_store(&flagS[b],
                                   TAG64 | (unsigned long long)__float_as_uint(p),
                                   __ATOMIC_RELAXED, __HIP_MEMORY_SCOPE_AGENT);
        }
    }

    // ---- Exchange: poll all 32 payload flags (parallel, 32 lanes) ----
    float f = 0.f;
    if (t < NTAIL) {
        unsigned long long v;
        while (((v = __hip_atomic_load(&flagS[t], __ATOMIC_RELAXED,
                                       __HIP_MEMORY_SCOPE_AGENT)) >> 32) != TAG32)
            __builtin_amdgcn_s_sleep(1);
        f = __uint_as_float((unsigned int)v);
    }

    // ---- Combine: wave-0 fixed-order sum (deterministic) ----
    if (t < 64) {
        float ssum = 0.f;
        #pragma unroll
        for (int i = 0; i < NTAIL; ++i)
            ssum += __shfl(f, i, 64);
        if (t == 0) sval = fmaxf(b2r + ssum, 0.0f);
    }
    __syncthreads();

    // ---- Fan-out: 32 blocks x 128 float4 = 16384 floats ----
    const float v = sval;
    if (t < 128)
        ((float4*)out)[b * 128 + t] = make_float4(v, v, v, v);
}

// ---------------- Fallback (ws_size too small; not expected) ----------------
__global__ __launch_bounds__(256) void colsum_dyn(const float* __restrict__ x,
                                                  float* __restrict__ wsA, int nb) {
    const int t = threadIdx.x, c4 = t & 63, rofs = t >> 6, bid = blockIdx.x;
    const float4* __restrict__ x4 = (const float4*)x;
    float4 acc = make_float4(0.f, 0.f, 0.f, 0.f);
    for (int r = bid * 4 + rofs; r < NROWS; r += 4 * nb) {
        float4 v = x4[r * 64 + c4];
        acc.x += v.x; acc.y += v.y; acc.z += v.z; acc.w += v.w;
    }
    __shared__ float4 s[256];
    s[t] = acc; __syncthreads();
    if (t < 64) {
        float4 a = s[t], b = s[t+64], c = s[t+128], d = s[t+192];
        float4 r; r.x=a.x+b.x+c.x+d.x; r.y=a.y+b.y+c.y+d.y;
        r.z=a.z+b.z+c.z+d.z; r.w=a.w+b.w+c.w+d.w;
        ((float4*)wsA)[bid * 64 + t] = r;
    }
}
__global__ __launch_bounds__(512) void hidden_dyn(const float* __restrict__ wsA,
                                                  const float* __restrict__ W1,
                                                  const float* __restrict__ b1,
                                                  const float* __restrict__ W2,
                                                  float* __restrict__ wsB, int nb) {
    __shared__ float4 tmp4[512];
    __shared__ float colmean[NCOLS];
    __shared__ float part[512];
    const int t = threadIdx.x, b = blockIdx.x;
    {
        const int c4 = t & 63, g = t >> 6, per = nb >> 3;
        const float4* __restrict__ w4 = (const float4*)wsA;
        float4 acc = make_float4(0.f, 0.f, 0.f, 0.f);
        for (int k = g * per; k < g * per + per; ++k) {
            float4 v = w4[k * 64 + c4];
            acc.x += v.x; acc.y += v.y; acc.z += v.z; acc.w += v.w;
        }
        tmp4[t] = acc; __syncthreads();
        if (t < 64) {
            float4 a = tmp4[t];
            for (int g2 = 1; g2 < 8; ++g2) {
                float4 v = tmp4[g2 * 64 + t];
                a.x += v.x; a.y += v.y; a.z += v.z; a.w += v.w;
            }
            const float inv = 1.0f / (float)NNODES;
            a.x *= inv; a.y *= inv; a.z *= inv; a.w *= inv;
            ((float4*)colmean)[t] = a;
        }
        __syncthreads();
    }
    const int w = t >> 6, l = t & 63, myt = b * 64 + l;
    float pa = 0.f;
    for (int c = w * 32; c < w * 32 + 32; ++c)
        pa = fmaf(colmean[c], W1[c * HID + myt], pa);
    part[t] = pa; __syncthreads();
    if (t < 64) {
        float hs = b1[myt];
        for (int g = 0; g < 8; ++g) hs += part[g * 64 + l];
        const float h = fmaxf(hs, 0.0f);
        float p = h * W2[myt];
        for (int off = 32; off > 0; off >>= 1) p += __shfl_down(p, off, 64);
        if (l == 0) wsB[b] = p;
    }
}
__global__ __launch_bounds__(256) void bcast_dyn(const float* __restrict__ wsB,
                                                 const float* __restrict__ b2,
                                                 float* __restrict__ out) {
    __shared__ float sval;
    if (threadIdx.x == 0) {
        float s = b2[0];
        for (int i = 0; i < 8; ++i) s += wsB[i];
        sval = fmaxf(s, 0.0f);
    }
    __syncthreads();
    const float v = sval;
    ((float4*)out)[blockIdx.x * 256 + threadIdx.x] = make_float4(v, v, v, v);
}

extern "C" void kernel_launch(void* const* d_in, const int* in_sizes, int n_in,
                              void* d_out, int out_size, void* d_ws, size_t ws_size,
                              hipStream_t stream) {
    const float* x  = (const float*)d_in[0];
    const float* W1 = (const float*)d_in[1];
    const float* b1 = (const float*)d_in[2];
    const float* W2 = (const float*)d_in[3];
    const float* b2 = (const float*)d_in[4];
    float* out = (float*)d_out;
    float* ws  = (float*)d_ws;

    if (ws_size >= (size_t)WS_FLOATS_NEEDED * sizeof(float)) {
        float*              wsA   = ws;
        unsigned long long* flagS = (unsigned long long*)(ws + 53248);
        colsum_split8<<<256, 256, 0, stream>>>(x, W1, wsA);
        tail_kernel<<<NTAIL, 512, 0, stream>>>(wsA, W1, b1, W2, b2, flagS, out);
    } else {
        int nb = (int)((ws_size / sizeof(float) - 8) / NCOLS);
        nb &= ~7; if (nb < 8) nb = 8;
        float* wsA = ws;
        float* wsB = ws + (size_t)nb * NCOLS;
        colsum_dyn<<<nb, 256, 0, stream>>>(x, wsA, nb);
        hidden_dyn<<<8, 512, 0, stream>>>(wsA, W1, b1, W2, wsB, nb);
        bcast_dyn<<<16, 256, 0, stream>>>(wsB, b2, out);
    }
}

// Round 17
// 13.450 us; speedup vs baseline: 1.0619x; 1.0619x over previous
//
#include <hip/hip_runtime.h>

// Problem constants (fixed by the reference)
#define NROWS   12288   // NUM_INPUT_ROWS
#define NCOLS   256     // CODEBOOK_DIM
#define HID     512     // HIDDEN_DIM
#define NNODES  16384   // NUM_NODES (zero-padded rows contribute nothing)
#define NPART   32      // partial rows (tail Phase A reads [32][256] = 32 KB)
#define NTAIL   16      // tail blocks (32 hidden dims / 32 KB W1 each) -- optimum
#define TAG32   0xB5297A4Du          // R15's tag
#define TAG64   ((unsigned long long)TAG32 << 32)

// ws float-index layout:
//   [0, 8192)        wsA partials [32][256]
//   [53248, 53280)   flagS[16] (u64 payload flags, 8B aligned)
#define WS_FLOATS_NEEDED 53280

// ---------------------------------------------------------------------------
// K1 (8-way column-split + W1 prime): 256 blocks x 256 threads.
// Proven best (R14/R15): all 256 CUs, 12 unrolled float4 loads/thread,
// W1 pulled into L3 during the x-read.
// ---------------------------------------------------------------------------
__global__ __launch_bounds__(256) void colsum_split8(const float* __restrict__ x,
                                                     const float* __restrict__ W1,
                                                     float* __restrict__ wsA) {
    const int t     = threadIdx.x;
    const int c4    = t & 7;             // float4 col within eighth
    const int rofs  = t >> 3;            // 0..31
    const int bid   = blockIdx.x;        // 0..255
    const int prow  = bid & 31;          // partial row
    const int cbase = (bid >> 5) * 8;    // float4 col base: 0,8,...,56
    const float4* __restrict__ x4 = (const float4*)x;

    // ---- W1 L3-prime (independent; overlaps the x-read) ----
    {
        const float4* __restrict__ W1_4 = (const float4*)W1;
        float4 wv = W1_4[(bid & 127) * 256 + t];
        asm volatile("" :: "v"(wv.x), "v"(wv.y), "v"(wv.z), "v"(wv.w));
    }

    // ---- Colsum: rows [prow*384, +384), this block's column-eighth ----
    float4 acc = make_float4(0.f, 0.f, 0.f, 0.f);
    #pragma unroll
    for (int k = 0; k < 12; ++k) {
        const int r = prow * 384 + rofs + k * 32;
        float4 v = x4[r * 64 + cbase + c4];
        acc.x += v.x; acc.y += v.y; acc.z += v.z; acc.w += v.w;
    }

    __shared__ float4 s[256];
    s[t] = acc;
    __syncthreads();
    if (t < 64) {
        float4 a = s[t], b = s[t + 64], c = s[t + 128], d = s[t + 192];
        float4 r;
        r.x = a.x + b.x + c.x + d.x;
        r.y = a.y + b.y + c.y + d.y;
        r.z = a.z + b.z + c.z + d.z;
        r.w = a.w + b.w + c.w + d.w;
        s[t] = r;
    }
    __syncthreads();
    if (t < 8) {
        float4 a = s[t];
        #pragma unroll
        for (int g = 1; g < 8; ++g) {
            float4 v = s[g * 8 + t];
            a.x += v.x; a.y += v.y; a.z += v.z; a.w += v.w;
        }
        ((float4*)wsA)[prow * 64 + cbase + t] = a;
    }
}

// ---------------------------------------------------------------------------
// K2 (tail): 16 blocks x 512 threads. Block b owns hidden dims [b*32, +32)
// -> 32 KB W1 per block. Proven optimum (R15).
// ---------------------------------------------------------------------------
__global__ __launch_bounds__(512) void tail_kernel(const float* __restrict__ wsA,
                                                   const float* __restrict__ W1,
                                                   const float* __restrict__ b1,
                                                   const float* __restrict__ W2,
                                                   const float* __restrict__ b2,
                                                   unsigned long long* __restrict__ flagS,
                                                   float* __restrict__ out) {
    __shared__ float4 tmp4[512];
    __shared__ float  colmean[NCOLS];
    __shared__ float  part[512];
    __shared__ float  sval;

    const int t  = threadIdx.x;
    const int b  = blockIdx.x;       // 0..15
    const int g  = t >> 5;           // cgroup 0..15 -> c range [g*16, +16)
    const int dl = t & 31;           // dim-lane
    const int d  = b * 32 + dl;      // hidden dim

    // ---- Prefetch W1 chunk (16 scalar loads/thread, coalesced) ----
    float w1r[16];
    #pragma unroll
    for (int j = 0; j < 16; ++j)
        w1r[j] = W1[(g * 16 + j) * HID + d];
    float b1r = 0.f, w2r = 0.f, b2r = 0.f;
    if (t < 32) { b1r = b1[d]; w2r = W2[d]; b2r = b2[0]; }

    // ---- Phase A: reduce 32 partials -> colmean ----
    {
        const int w = t >> 6, l = t & 63;
        const float4* __restrict__ wsA4 = (const float4*)wsA;
        float4 acc = make_float4(0.f, 0.f, 0.f, 0.f);
        #pragma unroll
        for (int j = 0; j < NPART / 8; ++j) {
            float4 v = wsA4[(w * (NPART / 8) + j) * 64 + l];
            acc.x += v.x; acc.y += v.y; acc.z += v.z; acc.w += v.w;
        }
        tmp4[t] = acc;
        __syncthreads();
        if (t < 64) {
            float4 a = tmp4[t];
            #pragma unroll
            for (int gg = 1; gg < 8; ++gg) {
                float4 v = tmp4[gg * 64 + t];
                a.x += v.x; a.y += v.y; a.z += v.z; a.w += v.w;
            }
            const float inv = 1.0f / (float)NNODES;
            a.x *= inv; a.y *= inv; a.z *= inv; a.w *= inv;
            ((float4*)colmean)[t] = a;
        }
        __syncthreads();
    }

    // ---- Phase B: hidden chunk + partial s, publish payload flag ----
    {
        float pa = 0.f;
        #pragma unroll
        for (int j = 0; j < 16; ++j)
            pa = fmaf(colmean[g * 16 + j], w1r[j], pa);
        part[t] = pa;
        __syncthreads();

        if (t < 32) {
            float hs = b1r;
            #pragma unroll
            for (int gg = 0; gg < 16; ++gg)
                hs += part[gg * 32 + t];        // stride 32 -> conflict-free
            const float h = fmaxf(hs, 0.0f);

            float p = h * w2r;
            #pragma unroll
            for (int off = 16; off > 0; off >>= 1)
                p += __shfl_down(p, off, 32);
            if (t == 0)
                __hip_atomic_store(&flagS[b],
                                   TAG64 | (unsigned long long)__float_as_uint(p),
                                   __ATOMIC_RELAXED, __HIP_MEMORY_SCOPE_AGENT);
        }
    }

    // ---- Exchange: poll all 16 payload flags (parallel, 16 lanes) ----
    float f = 0.f;
    if (t < NTAIL) {
        unsigned long long v;
        while (((v = __hip_atomic_load(&flagS[t], __ATOMIC_RELAXED,
                                       __HIP_MEMORY_SCOPE_AGENT)) >> 32) != TAG32)
            __builtin_amdgcn_s_sleep(1);
        f = __uint_as_float((unsigned int)v);
    }

    // ---- Combine: wave-0 fixed-order sum (deterministic) ----
    if (t < 64) {
        float ssum = 0.f;
        #pragma unroll
        for (int i = 0; i < NTAIL; ++i)
            ssum += __shfl(f, i, 64);
        if (t == 0) sval = fmaxf(b2r + ssum, 0.0f);
    }
    __syncthreads();

    // ---- Fan-out: 16 blocks x 256 float4 = 16384 floats ----
    const float v = sval;
    if (t < 256)
        ((float4*)out)[b * 256 + t] = make_float4(v, v, v, v);
}

// ---------------- Fallback (ws_size too small; not expected) ----------------
__global__ __launch_bounds__(256) void colsum_dyn(const float* __restrict__ x,
                                                  float* __restrict__ wsA, int nb) {
    const int t = threadIdx.x, c4 = t & 63, rofs = t >> 6, bid = blockIdx.x;
    const float4* __restrict__ x4 = (const float4*)x;
    float4 acc = make_float4(0.f, 0.f, 0.f, 0.f);
    for (int r = bid * 4 + rofs; r < NROWS; r += 4 * nb) {
        float4 v = x4[r * 64 + c4];
        acc.x += v.x; acc.y += v.y; acc.z += v.z; acc.w += v.w;
    }
    __shared__ float4 s[256];
    s[t] = acc; __syncthreads();
    if (t < 64) {
        float4 a = s[t], b = s[t+64], c = s[t+128], d = s[t+192];
        float4 r; r.x=a.x+b.x+c.x+d.x; r.y=a.y+b.y+c.y+d.y;
        r.z=a.z+b.z+c.z+d.z; r.w=a.w+b.w+c.w+d.w;
        ((float4*)wsA)[bid * 64 + t] = r;
    }
}
__global__ __launch_bounds__(512) void hidden_dyn(const float* __restrict__ wsA,
                                                  const float* __restrict__ W1,
                                                  const float* __restrict__ b1,
                                                  const float* __restrict__ W2,
                                                  float* __restrict__ wsB, int nb) {
    __shared__ float4 tmp4[512];
    __shared__ float colmean[NCOLS];
    __shared__ float part[512];
    const int t = threadIdx.x, b = blockIdx.x;
    {
        const int c4 = t & 63, g = t >> 6, per = nb >> 3;
        const float4* __restrict__ w4 = (const float4*)wsA;
        float4 acc = make_float4(0.f, 0.f, 0.f, 0.f);
        for (int k = g * per; k < g * per + per; ++k) {
            float4 v = w4[k * 64 + c4];
            acc.x += v.x; acc.y += v.y; acc.z += v.z; acc.w += v.w;
        }
        tmp4[t] = acc; __syncthreads();
        if (t < 64) {
            float4 a = tmp4[t];
            for (int g2 = 1; g2 < 8; ++g2) {
                float4 v = tmp4[g2 * 64 + t];
                a.x += v.x; a.y += v.y; a.z += v.z; a.w += v.w;
            }
            const float inv = 1.0f / (float)NNODES;
            a.x *= inv; a.y *= inv; a.z *= inv; a.w *= inv;
            ((float4*)colmean)[t] = a;
        }
        __syncthreads();
    }
    const int w = t >> 6, l = t & 63, myt = b * 64 + l;
    float pa = 0.f;
    for (int c = w * 32; c < w * 32 + 32; ++c)
        pa = fmaf(colmean[c], W1[c * HID + myt], pa);
    part[t] = pa; __syncthreads();
    if (t < 64) {
        float hs = b1[myt];
        for (int g = 0; g < 8; ++g) hs += part[g * 64 + l];
        const float h = fmaxf(hs, 0.0f);
        float p = h * W2[myt];
        for (int off = 32; off > 0; off >>= 1) p += __shfl_down(p, off, 64);
        if (l == 0) wsB[b] = p;
    }
}
__global__ __launch_bounds__(256) void bcast_dyn(const float* __restrict__ wsB,
                                                 const float* __restrict__ b2,
                                                 float* __restrict__ out) {
    __shared__ float sval;
    if (threadIdx.x == 0) {
        float s = b2[0];
        for (int i = 0; i < 8; ++i) s += wsB[i];
        sval = fmaxf(s, 0.0f);
    }
    __syncthreads();
    const float v = sval;
    ((float4*)out)[blockIdx.x * 256 + threadIdx.x] = make_float4(v, v, v, v);
}

extern "C" void kernel_launch(void* const* d_in, const int* in_sizes, int n_in,
                              void* d_out, int out_size, void* d_ws, size_t ws_size,
                              hipStream_t stream) {
    const float* x  = (const float*)d_in[0];
    const float* W1 = (const float*)d_in[1];
    const float* b1 = (const float*)d_in[2];
    const float* W2 = (const float*)d_in[3];
    const float* b2 = (const float*)d_in[4];
    float* out = (float*)d_out;
    float* ws  = (float*)d_ws;

    if (ws_size >= (size_t)WS_FLOATS_NEEDED * sizeof(float)) {
        float*              wsA   = ws;
        unsigned long long* flagS = (unsigned long long*)(ws + 53248);
        colsum_split8<<<256, 256, 0, stream>>>(x, W1, wsA);
        tail_kernel<<<NTAIL, 512, 0, stream>>>(wsA, W1, b1, W2, b2, flagS, out);
    } else {
        int nb = (int)((ws_size / sizeof(float) - 8) / NCOLS);
        nb &= ~7; if (nb < 8) nb = 8;
        float* wsA = ws;
        float* wsB = ws + (size_t)nb * NCOLS;
        colsum_dyn<<<nb, 256, 0, stream>>>(x, wsA, nb);
        hidden_dyn<<<8, 512, 0, stream>>>(wsA, W1, b1, W2, wsB, nb);
        bcast_dyn<<<16, 256, 0, stream>>>(wsB, b2, out);
    }
}